// Round 1
// baseline (324.767 us; speedup 1.0000x reference)
//
#include <hip/hip_runtime.h>

// MultiplicativeAttention: B=8, QL=SL=2048, QD=SD=OD=512
//   qw = q@w; scores = qw@s^T (mask -> -1e10); attn_w = softmax(scores);
//   attn_out = (attn_w @ s) @ out_w^T + out_b
// Outputs (fp32, concat): attn_w [8*2048*2048], attn_out [8*2048*512]

#define NEG_INF -10000000000.0f

typedef __attribute__((ext_vector_type(8))) short short8;   // 8 bf16 (4 VGPRs)
typedef __attribute__((ext_vector_type(4))) float floatx4;  // MFMA acc

__device__ __forceinline__ unsigned short f2u(float x) {
  // fp32 -> bf16 bits, round-to-nearest-even
  unsigned int u = __float_as_uint(x);
  unsigned int r = (u + 0x7fffu + ((u >> 16) & 1u)) >> 16;
  return (unsigned short)r;
}

// ---------------------------------------------------------------------------
// cast fp32 [R][C] -> bf16 straight copy (dN, [R][C]) and/or transpose (dT, [C][R])
// grid: (C/32, R/32, batch), block: (32,8)
__global__ void cast_nt(const float* __restrict__ src,
                        unsigned short* __restrict__ dN,
                        unsigned short* __restrict__ dT, int R, int C) {
  __shared__ unsigned short t[32][33];
  const int b = blockIdx.z;
  const size_t boff = (size_t)b * R * C;
  const int r0 = blockIdx.y * 32, c0 = blockIdx.x * 32;
  const int tx = threadIdx.x;
  for (int i = threadIdx.y; i < 32; i += 8) {
    unsigned short u = f2u(src[boff + (size_t)(r0 + i) * C + c0 + tx]);
    t[i][tx] = u;
    if (dN) dN[boff + (size_t)(r0 + i) * C + c0 + tx] = u;
  }
  __syncthreads();
  if (dT)
    for (int i = threadIdx.y; i < 32; i += 8)
      dT[boff + (size_t)(c0 + i) * R + r0 + tx] = t[tx][i];
}

// ---------------------------------------------------------------------------
// GEMM: C[m][n] = sum_k A[m][k] * Bt[n][k]   (Bt is B^T, row-major [N][K])
// 128x128 tile, BK=32, 4 waves (2x2), each wave 64x64 = 4x4 frags of 16x16x32.
// AF32: A is fp32 (reg-staged + converted); else A is bf16 (global_load_lds).
// OUT_MODE: 0 = bf16 out; 1 = fp32 out with column mask -> NEG_INF; 2 = fp32 + bias
template <int AF32, int OUT_MODE>
__global__ __launch_bounds__(256) void gemm_bt(
    const void* __restrict__ A_, const unsigned short* __restrict__ Bt_,
    void* __restrict__ C_, const int* __restrict__ mask_,
    const float* __restrict__ bias, int N, int K,
    long long aStride, long long bStride, long long cStride, int maskStride) {
  __shared__ unsigned short As[128 * 32];
  __shared__ unsigned short Bs[128 * 32];

  const int tid = threadIdx.x;
  const int lane = tid & 63, wave = tid >> 6;
  const int wr = wave >> 1, wc = wave & 1;
  const int l16 = lane & 15, lh = lane >> 4;
  const int z = blockIdx.z;
  const int m0 = blockIdx.y * 128, n0 = blockIdx.x * 128;

  const unsigned short* Bt = Bt_ + (size_t)z * bStride;

  floatx4 acc[4][4] = {};

  for (int k0 = 0; k0 < K; k0 += 32) {
    float4 av[4];
    if constexpr (AF32) {
      const float* A = (const float*)A_ + (size_t)z * aStride;
#pragma unroll
      for (int i = 0; i < 4; ++i) {
        int e = (i * 256 + tid) * 4;
        int row = e >> 5, kk = e & 31;
        av[i] = *(const float4*)(A + (size_t)(m0 + row) * K + k0 + kk);
      }
    }
    __syncthreads();  // previous iteration's LDS readers done
    if constexpr (AF32) {
#pragma unroll
      for (int i = 0; i < 4; ++i) {
        int e = (i * 256 + tid) * 4;
        unsigned short b4[4] = {f2u(av[i].x), f2u(av[i].y), f2u(av[i].z), f2u(av[i].w)};
        *(uint2*)&As[e] = *(uint2*)b4;
      }
    } else {
      const unsigned short* A = (const unsigned short*)A_ + (size_t)z * aStride;
#pragma unroll
      for (int i = 0; i < 2; ++i) {
        int chunk = i * 4 + wave;
        int e = chunk * 512 + lane * 8;
        int row = e >> 5, kk = e & 31;
        __builtin_amdgcn_global_load_lds(
            (const __attribute__((address_space(1))) void*)(A + (size_t)(m0 + row) * K + k0 + kk),
            (__attribute__((address_space(3))) void*)(As + chunk * 512), 16, 0, 0);
      }
    }
#pragma unroll
    for (int i = 0; i < 2; ++i) {
      int chunk = i * 4 + wave;
      int e = chunk * 512 + lane * 8;
      int row = e >> 5, kk = e & 31;
      __builtin_amdgcn_global_load_lds(
          (const __attribute__((address_space(1))) void*)(Bt + (size_t)(n0 + row) * K + k0 + kk),
          (__attribute__((address_space(3))) void*)(Bs + chunk * 512), 16, 0, 0);
    }
    __syncthreads();  // staging complete (compiler drains vmcnt/lgkmcnt)

    short8 af[4], bfr[4];
#pragma unroll
    for (int m = 0; m < 4; ++m)
      af[m] = *(const short8*)&As[(wr * 64 + m * 16 + l16) * 32 + lh * 8];
#pragma unroll
    for (int n = 0; n < 4; ++n)
      bfr[n] = *(const short8*)&Bs[(wc * 64 + n * 16 + l16) * 32 + lh * 8];
#pragma unroll
    for (int m = 0; m < 4; ++m)
#pragma unroll
      for (int n = 0; n < 4; ++n)
        acc[m][n] = __builtin_amdgcn_mfma_f32_16x16x32_bf16(af[m], bfr[n], acc[m][n], 0, 0, 0);
  }

  const int rbase = m0 + wr * 64, cbase = n0 + wc * 64;
  if constexpr (OUT_MODE == 0) {
    unsigned short* C = (unsigned short*)C_ + (size_t)z * cStride;
#pragma unroll
    for (int m = 0; m < 4; ++m)
#pragma unroll
      for (int n = 0; n < 4; ++n) {
        int row = rbase + m * 16 + lh * 4;
        int col = cbase + n * 16 + l16;
#pragma unroll
        for (int j = 0; j < 4; ++j)
          C[(size_t)(row + j) * N + col] = f2u(acc[m][n][j]);
      }
  } else if constexpr (OUT_MODE == 1) {
    float* C = (float*)C_ + (size_t)z * cStride;
    const int* mk = mask_ + (size_t)z * maskStride;
#pragma unroll
    for (int n = 0; n < 4; ++n) {
      int col = cbase + n * 16 + l16;
      bool keep = mk[col] != 0;
#pragma unroll
      for (int m = 0; m < 4; ++m) {
        int row = rbase + m * 16 + lh * 4;
#pragma unroll
        for (int j = 0; j < 4; ++j)
          C[(size_t)(row + j) * N + col] = keep ? acc[m][n][j] : NEG_INF;
      }
    }
  } else {
    float* C = (float*)C_ + (size_t)z * cStride;
#pragma unroll
    for (int n = 0; n < 4; ++n) {
      int col = cbase + n * 16 + l16;
      float bv = bias[col];
#pragma unroll
      for (int m = 0; m < 4; ++m) {
        int row = rbase + m * 16 + lh * 4;
#pragma unroll
        for (int j = 0; j < 4; ++j)
          C[(size_t)(row + j) * N + col] = acc[m][n][j] + bv;
      }
    }
  }
}

// ---------------------------------------------------------------------------
// In-place row softmax over 2048 fp32 elements. 1 block (256 thr) per row.
__global__ __launch_bounds__(256) void softmax_rows(float* __restrict__ sc) {
  float* p = sc + (size_t)blockIdx.x * 2048;
  const int tid = threadIdx.x, lane = tid & 63, wave = tid >> 6;
  float4 v0 = ((float4*)p)[tid];
  float4 v1 = ((float4*)p)[tid + 256];
  float mx = fmaxf(fmaxf(fmaxf(v0.x, v0.y), fmaxf(v0.z, v0.w)),
                   fmaxf(fmaxf(v1.x, v1.y), fmaxf(v1.z, v1.w)));
#pragma unroll
  for (int o = 32; o; o >>= 1) mx = fmaxf(mx, __shfl_xor(mx, o));
  __shared__ float red[4], red2[4];
  if (lane == 0) red[wave] = mx;
  __syncthreads();
  mx = fmaxf(fmaxf(red[0], red[1]), fmaxf(red[2], red[3]));
  v0.x = expf(v0.x - mx); v0.y = expf(v0.y - mx);
  v0.z = expf(v0.z - mx); v0.w = expf(v0.w - mx);
  v1.x = expf(v1.x - mx); v1.y = expf(v1.y - mx);
  v1.z = expf(v1.z - mx); v1.w = expf(v1.w - mx);
  float s = v0.x + v0.y + v0.z + v0.w + v1.x + v1.y + v1.z + v1.w;
#pragma unroll
  for (int o = 32; o; o >>= 1) s += __shfl_xor(s, o);
  if (lane == 0) red2[wave] = s;
  __syncthreads();
  float inv = 1.0f / (red2[0] + red2[1] + red2[2] + red2[3]);
  v0.x *= inv; v0.y *= inv; v0.z *= inv; v0.w *= inv;
  v1.x *= inv; v1.y *= inv; v1.z *= inv; v1.w *= inv;
  ((float4*)p)[tid] = v0;
  ((float4*)p)[tid + 256] = v1;
}

// ---------------------------------------------------------------------------
extern "C" void kernel_launch(void* const* d_in, const int* in_sizes, int n_in,
                              void* d_out, int out_size, void* d_ws, size_t ws_size,
                              hipStream_t stream) {
  const float* q = (const float*)d_in[0];      // [8,2048,512]
  const float* s = (const float*)d_in[1];      // [8,2048,512]
  const int* mask = (const int*)d_in[2];       // [8,1,2048]
  const float* w = (const float*)d_in[3];      // [512,512]
  const float* out_w = (const float*)d_in[4];  // [512,512]
  const float* out_b = (const float*)d_in[5];  // [512]

  float* attn_w = (float*)d_out;                                 // [8,2048,2048]
  float* attn_out = (float*)d_out + (size_t)8 * 2048 * 2048;     // [8,2048,512]

  // workspace layout (bytes): needs ~68 MB
  char* ws = (char*)d_ws;
  const size_t MB = 1024 * 1024;
  unsigned short* qw  = (unsigned short*)(ws);            // [16384,512] bf16, 16MB
  unsigned short* sN  = (unsigned short*)(ws + 16 * MB);  // [8,2048,512] bf16
  unsigned short* sT  = (unsigned short*)(ws + 32 * MB);  // [8,512,2048] bf16
  unsigned short* pre = (unsigned short*)(ws + 48 * MB);  // [16384,512] bf16
  unsigned short* wT  = (unsigned short*)(ws + 64 * MB);  // [512,512] w^T
  unsigned short* owN = (unsigned short*)(ws + 65 * MB);  // [512,512] out_w

  dim3 tb(32, 8);
  // casts / transposes
  cast_nt<<<dim3(16, 64, 8), tb, 0, stream>>>(s, sN, sT, 2048, 512);
  cast_nt<<<dim3(16, 16, 1), tb, 0, stream>>>(w, nullptr, wT, 512, 512);
  cast_nt<<<dim3(16, 16, 1), tb, 0, stream>>>(out_w, owN, nullptr, 512, 512);

  // GEMM1: qw[16384,512] = q @ w   (A fp32, Bt = w^T, out bf16)
  gemm_bt<1, 0><<<dim3(4, 128, 1), 256, 0, stream>>>(
      q, wT, qw, nullptr, nullptr, 512, 512, 0, 0, 0, 0);

  // GEMM2: scores[b,2048,2048] = qw @ s^T, masked, fp32 into d_out (scratch in-place)
  gemm_bt<0, 1><<<dim3(16, 16, 8), 256, 0, stream>>>(
      qw, sN, attn_w, mask, nullptr, 2048, 512,
      2048LL * 512, 2048LL * 512, 2048LL * 2048, 2048);

  // softmax rows in place
  softmax_rows<<<16384, 256, 0, stream>>>(attn_w);

  // GEMM3: pre[b,2048,512] = attn_w @ s   (A fp32 from d_out, Bt = s^T, out bf16)
  gemm_bt<1, 0><<<dim3(4, 16, 8), 256, 0, stream>>>(
      attn_w, sT, pre, nullptr, nullptr, 512, 2048,
      2048LL * 2048, 512LL * 2048, 2048LL * 512, 0);

  // GEMM4: attn_out[16384,512] = pre @ out_w^T + out_b  (fp32 out)
  gemm_bt<0, 2><<<dim3(4, 128, 1), 256, 0, stream>>>(
      pre, owN, attn_out, nullptr, out_b, 512, 512, 0, 0, 0, 0);

  (void)in_sizes; (void)n_in; (void)out_size; (void)ws_size;
}

// Round 2
// 249.946 us; speedup vs baseline: 1.2993x; 1.2993x over previous
//
#include <hip/hip_runtime.h>

// MultiplicativeAttention: B=8, QL=SL=2048, QD=SD=OD=512
//   qw = q@w; scores = qw@s^T (mask -> -1e10); attn_w = softmax(scores);
//   attn_out = (attn_w @ s) @ out_w^T + out_b
// Outputs (fp32, concat): attn_w [8*2048*2048], attn_out [8*2048*512]

#define NEG_INF -10000000000.0f

typedef __attribute__((ext_vector_type(8))) short short8;   // 8 bf16 (4 VGPRs)
typedef __attribute__((ext_vector_type(4))) float floatx4;  // MFMA acc

__device__ __forceinline__ unsigned short f2u(float x) {
  // fp32 -> bf16 bits, round-to-nearest-even
  unsigned int u = __float_as_uint(x);
  unsigned int r = (u + 0x7fffu + ((u >> 16) & 1u)) >> 16;
  return (unsigned short)r;
}

// ---------------------------------------------------------------------------
// cast fp32 [R][C] -> bf16 straight copy (dN, [R][C]) and/or transpose (dT, [C][R])
// grid: (C/32, R/32, batch), block: (32,8)
__global__ void cast_nt(const float* __restrict__ src,
                        unsigned short* __restrict__ dN,
                        unsigned short* __restrict__ dT, int R, int C) {
  __shared__ unsigned short t[32][33];
  const int b = blockIdx.z;
  const size_t boff = (size_t)b * R * C;
  const int r0 = blockIdx.y * 32, c0 = blockIdx.x * 32;
  const int tx = threadIdx.x;
  for (int i = threadIdx.y; i < 32; i += 8) {
    unsigned short u = f2u(src[boff + (size_t)(r0 + i) * C + c0 + tx]);
    t[i][tx] = u;
    if (dN) dN[boff + (size_t)(r0 + i) * C + c0 + tx] = u;
  }
  __syncthreads();
  if (dT)
    for (int i = threadIdx.y; i < 32; i += 8)
      dT[boff + (size_t)(c0 + i) * R + r0 + tx] = t[tx][i];
}

// ---------------------------------------------------------------------------
// Generic GEMM: C[m][n] = sum_k A[m][k] * Bt[n][k]   (Bt row-major [N][K])
// 128x128 tile, BK=32, 4 waves (2x2), each wave 64x64 = 4x4 frags of 16x16x32.
// AF32: A fp32 (reg-staged + converted); else A bf16 (global_load_lds).
// OUT_MODE: 0 = bf16 out; 1 = fp32 out + column mask -> NEG_INF; 2 = fp32 + bias
template <int AF32, int OUT_MODE>
__global__ __launch_bounds__(256) void gemm_bt(
    const void* __restrict__ A_, const unsigned short* __restrict__ Bt_,
    void* __restrict__ C_, const int* __restrict__ mask_,
    const float* __restrict__ bias, int N, int K,
    long long aStride, long long bStride, long long cStride, int maskStride) {
  __shared__ unsigned short As[128 * 32];
  __shared__ unsigned short Bs[128 * 32];

  const int tid = threadIdx.x;
  const int lane = tid & 63, wave = tid >> 6;
  const int wr = wave >> 1, wc = wave & 1;
  const int l16 = lane & 15, lh = lane >> 4;
  const int z = blockIdx.z;
  const int m0 = blockIdx.y * 128, n0 = blockIdx.x * 128;

  const unsigned short* Bt = Bt_ + (size_t)z * bStride;

  floatx4 acc[4][4] = {};

  for (int k0 = 0; k0 < K; k0 += 32) {
    float4 av[4];
    if constexpr (AF32) {
      const float* A = (const float*)A_ + (size_t)z * aStride;
#pragma unroll
      for (int i = 0; i < 4; ++i) {
        int e = (i * 256 + tid) * 4;
        int row = e >> 5, kk = e & 31;
        av[i] = *(const float4*)(A + (size_t)(m0 + row) * K + k0 + kk);
      }
    }
    __syncthreads();  // previous iteration's LDS readers done
    if constexpr (AF32) {
#pragma unroll
      for (int i = 0; i < 4; ++i) {
        int e = (i * 256 + tid) * 4;
        unsigned short b4[4] = {f2u(av[i].x), f2u(av[i].y), f2u(av[i].z), f2u(av[i].w)};
        *(uint2*)&As[e] = *(uint2*)b4;
      }
    } else {
      const unsigned short* A = (const unsigned short*)A_ + (size_t)z * aStride;
#pragma unroll
      for (int i = 0; i < 2; ++i) {
        int chunk = i * 4 + wave;
        int e = chunk * 512 + lane * 8;
        int row = e >> 5, kk = e & 31;
        __builtin_amdgcn_global_load_lds(
            (const __attribute__((address_space(1))) void*)(A + (size_t)(m0 + row) * K + k0 + kk),
            (__attribute__((address_space(3))) void*)(As + chunk * 512), 16, 0, 0);
      }
    }
#pragma unroll
    for (int i = 0; i < 2; ++i) {
      int chunk = i * 4 + wave;
      int e = chunk * 512 + lane * 8;
      int row = e >> 5, kk = e & 31;
      __builtin_amdgcn_global_load_lds(
          (const __attribute__((address_space(1))) void*)(Bt + (size_t)(n0 + row) * K + k0 + kk),
          (__attribute__((address_space(3))) void*)(Bs + chunk * 512), 16, 0, 0);
    }
    __syncthreads();  // staging complete

    short8 af[4], bfr[4];
#pragma unroll
    for (int m = 0; m < 4; ++m)
      af[m] = *(const short8*)&As[(wr * 64 + m * 16 + l16) * 32 + lh * 8];
#pragma unroll
    for (int n = 0; n < 4; ++n)
      bfr[n] = *(const short8*)&Bs[(wc * 64 + n * 16 + l16) * 32 + lh * 8];
#pragma unroll
    for (int m = 0; m < 4; ++m)
#pragma unroll
      for (int n = 0; n < 4; ++n)
        acc[m][n] = __builtin_amdgcn_mfma_f32_16x16x32_bf16(af[m], bfr[n], acc[m][n], 0, 0, 0);
  }

  const int rbase = m0 + wr * 64, cbase = n0 + wc * 64;
  if constexpr (OUT_MODE == 0) {
    unsigned short* C = (unsigned short*)C_ + (size_t)z * cStride;
#pragma unroll
    for (int m = 0; m < 4; ++m)
#pragma unroll
      for (int n = 0; n < 4; ++n) {
        int row = rbase + m * 16 + lh * 4;
        int col = cbase + n * 16 + l16;
#pragma unroll
        for (int j = 0; j < 4; ++j)
          C[(size_t)(row + j) * N + col] = f2u(acc[m][n][j]);
      }
  } else if constexpr (OUT_MODE == 1) {
    float* C = (float*)C_ + (size_t)z * cStride;
    const int* mk = mask_ + (size_t)z * maskStride;
#pragma unroll
    for (int n = 0; n < 4; ++n) {
      int col = cbase + n * 16 + l16;
      bool keep = mk[col] != 0;
#pragma unroll
      for (int m = 0; m < 4; ++m) {
        int row = rbase + m * 16 + lh * 4;
#pragma unroll
        for (int j = 0; j < 4; ++j)
          C[(size_t)(row + j) * N + col] = keep ? acc[m][n][j] : NEG_INF;
      }
    }
  } else {
    float* C = (float*)C_ + (size_t)z * cStride;
#pragma unroll
    for (int n = 0; n < 4; ++n) {
      int col = cbase + n * 16 + l16;
      float bv = bias[col];
#pragma unroll
      for (int m = 0; m < 4; ++m) {
        int row = rbase + m * 16 + lh * 4;
#pragma unroll
        for (int j = 0; j < 4; ++j)
          C[(size_t)(row + j) * N + col] = acc[m][n][j] + bv;
      }
    }
  }
}

// ---------------------------------------------------------------------------
// PV GEMM: pre[b,2048,512] = attn_w(fp32) @ s.  Tile 64x512, BK=32, 8 waves
// (wave w owns cols [w*64, w*64+64)).  A read from HBM exactly once.
// 2-phase double-buffered LDS, counted vmcnt (never drain to 0 in main loop).
// Per thread per tile: 1 float4 A load (reg-staged, fp32->bf16) + 4
// global_load_lds (B).  End-of-tile wait: vmcnt(1) keeps next A in flight.
__global__ __launch_bounds__(512) void gemm_pv(const float* __restrict__ P,
                                               const unsigned short* __restrict__ sT,
                                               unsigned short* __restrict__ pre) {
  __shared__ unsigned short As[2][64 * 32];
  __shared__ unsigned short Bs[2][512 * 32];
  const int tid = threadIdx.x, lane = tid & 63, w = tid >> 6;
  const int l16 = lane & 15, lh = lane >> 4;
  const int z = blockIdx.x, m0 = blockIdx.y * 64;  // grid (8,32): XCD <- batch
  const float* Az = P + (size_t)z * 2048 * 2048;
  const unsigned short* Bz = sT + (size_t)z * 512 * 2048;
  const int arow = tid >> 3, akk = (tid & 7) * 4;
  const int aoff = arow * 32 + akk;      // As elem offset for this thread
  const int brow0 = (lane >> 2);         // + ch*16
  const int bkk = (lane & 3) * 8;
  const int NT = 64;                     // 2048 / 32

  floatx4 acc[4][4] = {};

  // ---- prologue: tile 0 staged, tile 1 A-load in flight
  float4 av = *(const float4*)(Az + (size_t)(m0 + arow) * 2048 + akk);
  {
    unsigned short b4[4] = {f2u(av.x), f2u(av.y), f2u(av.z), f2u(av.w)};
    *(uint2*)&As[0][aoff] = *(uint2*)b4;
  }
  __builtin_amdgcn_sched_barrier(0);
#pragma unroll
  for (int i = 0; i < 4; ++i) {
    int ch = w * 4 + i;
    __builtin_amdgcn_global_load_lds(
        (const __attribute__((address_space(1))) void*)(Bz + (size_t)(ch * 16 + brow0) * 2048 + bkk),
        (__attribute__((address_space(3))) void*)(&Bs[0][ch * 512]), 16, 0, 0);
  }
  __builtin_amdgcn_sched_barrier(0);
  av = *(const float4*)(Az + (size_t)(m0 + arow) * 2048 + 32 + akk);
  __builtin_amdgcn_sched_barrier(0);
  asm volatile("s_waitcnt vmcnt(1) lgkmcnt(0)" ::: "memory");  // B(0) done, av(1) in flight
  __builtin_amdgcn_s_barrier();

  for (int t = 0; t < NT; ++t) {
    const int cb = t & 1, nb = cb ^ 1;
    if (t + 1 < NT) {
      const int k1 = (t + 1) * 32;
#pragma unroll
      for (int i = 0; i < 4; ++i) {
        int ch = w * 4 + i;
        __builtin_amdgcn_global_load_lds(
            (const __attribute__((address_space(1))) void*)(Bz + (size_t)(ch * 16 + brow0) * 2048 + k1 + bkk),
            (__attribute__((address_space(3))) void*)(&Bs[nb][ch * 512]), 16, 0, 0);
      }
      __builtin_amdgcn_sched_barrier(0);
      {  // convert av (tile t+1) -> As[nb]; compiler emits counted vmcnt for av
        unsigned short b4[4] = {f2u(av.x), f2u(av.y), f2u(av.z), f2u(av.w)};
        *(uint2*)&As[nb][aoff] = *(uint2*)b4;
      }
      __builtin_amdgcn_sched_barrier(0);
      if (t + 2 < NT)
        av = *(const float4*)(Az + (size_t)(m0 + arow) * 2048 + (t + 2) * 32 + akk);
      __builtin_amdgcn_sched_barrier(0);
    }
    short8 af[4], bf[4];
#pragma unroll
    for (int m = 0; m < 4; ++m)
      af[m] = *(const short8*)&As[cb][(m * 16 + l16) * 32 + lh * 8];
#pragma unroll
    for (int nn = 0; nn < 4; ++nn)
      bf[nn] = *(const short8*)&Bs[cb][(w * 64 + nn * 16 + l16) * 32 + lh * 8];
#pragma unroll
    for (int m = 0; m < 4; ++m)
#pragma unroll
      for (int nn = 0; nn < 4; ++nn)
        acc[m][nn] = __builtin_amdgcn_mfma_f32_16x16x32_bf16(af[m], bf[nn], acc[m][nn], 0, 0, 0);
    if (t + 1 < NT) {
      if (t + 2 < NT)
        asm volatile("s_waitcnt vmcnt(1) lgkmcnt(0)" ::: "memory");  // B(t+1) done, av stays
      else
        asm volatile("s_waitcnt vmcnt(0) lgkmcnt(0)" ::: "memory");  // tail: drain
      __builtin_amdgcn_s_barrier();
    }
  }

  unsigned short* Cz = pre + (size_t)z * 2048 * 512;
#pragma unroll
  for (int m = 0; m < 4; ++m)
#pragma unroll
    for (int nn = 0; nn < 4; ++nn) {
      int row = m0 + m * 16 + lh * 4;
      int col = w * 64 + nn * 16 + l16;
#pragma unroll
      for (int j = 0; j < 4; ++j)
        Cz[(size_t)(row + j) * 512 + col] = f2u(acc[m][nn][j]);
    }
}

// ---------------------------------------------------------------------------
// In-place row softmax over 2048 fp32 elements. 1 block (256 thr) per row.
__global__ __launch_bounds__(256) void softmax_rows(float* __restrict__ sc) {
  float* p = sc + (size_t)blockIdx.x * 2048;
  const int tid = threadIdx.x, lane = tid & 63, wave = tid >> 6;
  float4 v0 = ((float4*)p)[tid];
  float4 v1 = ((float4*)p)[tid + 256];
  float mx = fmaxf(fmaxf(fmaxf(v0.x, v0.y), fmaxf(v0.z, v0.w)),
                   fmaxf(fmaxf(v1.x, v1.y), fmaxf(v1.z, v1.w)));
#pragma unroll
  for (int o = 32; o; o >>= 1) mx = fmaxf(mx, __shfl_xor(mx, o));
  __shared__ float red[4], red2[4];
  if (lane == 0) red[wave] = mx;
  __syncthreads();
  mx = fmaxf(fmaxf(red[0], red[1]), fmaxf(red[2], red[3]));
  v0.x = expf(v0.x - mx); v0.y = expf(v0.y - mx);
  v0.z = expf(v0.z - mx); v0.w = expf(v0.w - mx);
  v1.x = expf(v1.x - mx); v1.y = expf(v1.y - mx);
  v1.z = expf(v1.z - mx); v1.w = expf(v1.w - mx);
  float s = v0.x + v0.y + v0.z + v0.w + v1.x + v1.y + v1.z + v1.w;
#pragma unroll
  for (int o = 32; o; o >>= 1) s += __shfl_xor(s, o);
  if (lane == 0) red2[wave] = s;
  __syncthreads();
  float inv = 1.0f / (red2[0] + red2[1] + red2[2] + red2[3]);
  v0.x *= inv; v0.y *= inv; v0.z *= inv; v0.w *= inv;
  v1.x *= inv; v1.y *= inv; v1.z *= inv; v1.w *= inv;
  ((float4*)p)[tid] = v0;
  ((float4*)p)[tid + 256] = v1;
}

// ---------------------------------------------------------------------------
extern "C" void kernel_launch(void* const* d_in, const int* in_sizes, int n_in,
                              void* d_out, int out_size, void* d_ws, size_t ws_size,
                              hipStream_t stream) {
  const float* q = (const float*)d_in[0];      // [8,2048,512]
  const float* s = (const float*)d_in[1];      // [8,2048,512]
  const int* mask = (const int*)d_in[2];       // [8,1,2048]
  const float* w = (const float*)d_in[3];      // [512,512]
  const float* out_w = (const float*)d_in[4];  // [512,512]
  const float* out_b = (const float*)d_in[5];  // [512]

  float* attn_w = (float*)d_out;                                 // [8,2048,2048]
  float* attn_out = (float*)d_out + (size_t)8 * 2048 * 2048;     // [8,2048,512]

  // workspace layout (bytes): ~68 MB
  char* ws = (char*)d_ws;
  const size_t MB = 1024 * 1024;
  unsigned short* qw  = (unsigned short*)(ws);            // [16384,512] bf16
  unsigned short* sN  = (unsigned short*)(ws + 16 * MB);  // [8,2048,512] bf16
  unsigned short* sT  = (unsigned short*)(ws + 32 * MB);  // [8,512,2048] bf16
  unsigned short* pre = (unsigned short*)(ws + 48 * MB);  // [16384,512] bf16
  unsigned short* wT  = (unsigned short*)(ws + 64 * MB);  // [512,512] w^T
  unsigned short* owN = (unsigned short*)(ws + 65 * MB);  // [512,512] out_w

  dim3 tb(32, 8);
  cast_nt<<<dim3(16, 64, 8), tb, 0, stream>>>(s, sN, sT, 2048, 512);
  cast_nt<<<dim3(16, 16, 1), tb, 0, stream>>>(w, nullptr, wT, 512, 512);
  cast_nt<<<dim3(16, 16, 1), tb, 0, stream>>>(out_w, owN, nullptr, 512, 512);

  // GEMM1: qw[16384,512] = q @ w   (A fp32, Bt = w^T, out bf16)
  gemm_bt<1, 0><<<dim3(4, 128, 1), 256, 0, stream>>>(
      q, wT, qw, nullptr, nullptr, 512, 512, 0, 0, 0, 0);

  // GEMM2: scores = qw @ s^T, masked, fp32 into d_out (scratch in-place)
  gemm_bt<0, 1><<<dim3(16, 16, 8), 256, 0, stream>>>(
      qw, sN, attn_w, mask, nullptr, 2048, 512,
      2048LL * 512, 2048LL * 512, 2048LL * 2048, 2048);

  // softmax rows in place
  softmax_rows<<<16384, 256, 0, stream>>>(attn_w);

  // GEMM3: pre = attn_w @ s   (64x512 tile, A fetched once, counted-vmcnt dbuf)
  gemm_pv<<<dim3(8, 32), 512, 0, stream>>>(attn_w, sT, pre);

  // GEMM4: attn_out = pre @ out_w^T + out_b  (fp32 out)
  gemm_bt<0, 2><<<dim3(4, 128, 1), 256, 0, stream>>>(
      pre, owN, attn_out, nullptr, out_b, 512, 512, 0, 0, 0, 0);

  (void)in_sizes; (void)n_in; (void)out_size; (void)ws_size;
}